// Round 1
// baseline (1476.670 us; speedup 1.0000x reference)
//
#include <hip/hip_runtime.h>
#include <hip/hip_bf16.h>

// MultiScaleAttention on MI355X (gfx950).
// Pipeline: cvt(x)->bf16; QKV = x@Wqkv^T-layout GEMM (bf16 MFMA, fp32 acc);
// windowed attention with q max-pool (VALU, fp32); proj GEMM -> fp32 out.
// Batch chunked x4 so workspace ~197 MB.

typedef __bf16 bf16x8 __attribute__((ext_vector_type(8)));
typedef float f32x4 __attribute__((ext_vector_type(4)));

#define GLOBAL_AS __attribute__((address_space(1)))
#define LDS_AS __attribute__((address_space(3)))

__device__ __forceinline__ unsigned short f2bf(float f) {
    unsigned u = __builtin_bit_cast(unsigned, f);
    u += 0x7FFFu + ((u >> 16) & 1u);           // round-to-nearest-even
    return (unsigned short)(u >> 16);
}
__device__ __forceinline__ float bf2f(unsigned short h) {
    return __builtin_bit_cast(float, (unsigned)h << 16);
}

__device__ __forceinline__ void load16_to_lds(const void* g, void* l) {
    __builtin_amdgcn_global_load_lds((const GLOBAL_AS unsigned int*)g,
                                     (LDS_AS unsigned int*)l, 16, 0, 0);
}

// ---------------- elementwise fp32 -> bf16 ----------------
__global__ void cvt_f32_bf16(const float* __restrict__ in,
                             unsigned short* __restrict__ out, long n4) {
    long i = (long)blockIdx.x * blockDim.x + threadIdx.x;
    if (i >= n4) return;
    float4 f = ((const float4*)in)[i];
    uint2 u;
    u.x = (unsigned)f2bf(f.x) | ((unsigned)f2bf(f.y) << 16);
    u.y = (unsigned)f2bf(f.z) | ((unsigned)f2bf(f.w) << 16);
    ((uint2*)out)[i] = u;
}

// ---------------- W[K][N] fp32 -> Wt[N][K] bf16 ----------------
__global__ void transpose_cvt(const float* __restrict__ W,
                              unsigned short* __restrict__ Wt, int K, int N) {
    __shared__ float tile[32][33];
    int bx = blockIdx.x * 32;                  // N offset
    int by = blockIdx.y * 32;                  // K offset
    int tx = threadIdx.x & 31, ty = threadIdx.x >> 5;   // ty 0..7
    #pragma unroll
    for (int i = 0; i < 32; i += 8)
        tile[ty + i][tx] = W[(size_t)(by + ty + i) * N + bx + tx];
    __syncthreads();
    #pragma unroll
    for (int i = 0; i < 32; i += 8)
        Wt[(size_t)(bx + ty + i) * K + by + tx] = f2bf(tile[tx][ty + i]);
}

// ---------------- bf16 GEMM: C[M,N] = A[M,K] @ Bt[N,K]^T + bias ----------------
// 128x128 tile, BK=64, 256 threads = 4 waves (2x2 of 64x64), mfma 16x16x32.
// M%128==0, N%128==0, K%64==0 (all exact for this problem).
template <bool OUT_BF16>
__global__ __launch_bounds__(256)
void gemm_bt(const unsigned short* __restrict__ A,
             const unsigned short* __restrict__ Bt,
             const float* __restrict__ bias,
             void* __restrict__ Cv, int M, int N, int K) {
    __shared__ alignas(16) unsigned short lsA[128 * 64];
    __shared__ alignas(16) unsigned short lsB[128 * 64];

    const int tid  = threadIdx.x;
    const int lane = tid & 63;
    const int wave = tid >> 6;
    const int wm = (wave >> 1) * 64;
    const int wn = (wave & 1) * 64;
    const long bm = (long)blockIdx.y * 128;
    const long bn = (long)blockIdx.x * 128;

    // staging: flat byte f = tid*16 + it*4096 within row-major [128][64] bf16 tile
    const int arow  = tid >> 3;                // 0..31, +32 per it
    const int acolb = (tid & 7) * 16;          // byte col within 128-B row
    const char* gA = (const char*)A + ((bm + arow) * (long)K) * 2 + acolb;
    const char* gB = (const char*)Bt + ((bn + arow) * (long)K) * 2 + acolb;
    const long rowStep = (long)K * 2 * 32;     // 32 rows ahead per 'it'
    const int ldsWaveBase = wave * 512;        // ushort units (1024 B per wave)

    f32x4 acc[4][4] = {};

    for (int kt = 0; kt < K; kt += 64) {
        #pragma unroll
        for (int it = 0; it < 4; ++it) {
            load16_to_lds(gA + it * rowStep, &lsA[it * 2048 + ldsWaveBase]);
            load16_to_lds(gB + it * rowStep, &lsB[it * 2048 + ldsWaveBase]);
        }
        gA += 128; gB += 128;                  // advance 64 bf16 in K
        __syncthreads();
        #pragma unroll
        for (int ks = 0; ks < 64; ks += 32) {
            bf16x8 af[4], bg[4];
            const int koff = ks + (lane >> 4) * 8;
            #pragma unroll
            for (int i = 0; i < 4; ++i) {
                const int rowA = wm + i * 16 + (lane & 15);
                af[i] = *(const bf16x8*)&lsA[rowA * 64 + koff];
                const int rowB = wn + i * 16 + (lane & 15);
                bg[i] = *(const bf16x8*)&lsB[rowB * 64 + koff];
            }
            #pragma unroll
            for (int i = 0; i < 4; ++i)
                #pragma unroll
                for (int j = 0; j < 4; ++j)
                    acc[i][j] = __builtin_amdgcn_mfma_f32_16x16x32_bf16(
                        af[i], bg[j], acc[i][j], 0, 0, 0);
        }
        __syncthreads();
    }

    // epilogue: D[row=(lane>>4)*4+r][col=lane&15] per 16x16 tile
    const long rbase = bm + wm + (lane >> 4) * 4;
    const int  cbase = (int)bn + wn + (lane & 15);
    #pragma unroll
    for (int j = 0; j < 4; ++j) {
        const int col = cbase + j * 16;
        const float bv = bias[col];
        #pragma unroll
        for (int i = 0; i < 4; ++i) {
            const long row0 = rbase + i * 16;
            #pragma unroll
            for (int r = 0; r < 4; ++r) {
                const float v = acc[i][j][r] + bv;
                const size_t idx = (size_t)(row0 + r) * N + col;
                if constexpr (OUT_BF16) ((unsigned short*)Cv)[idx] = f2bf(v);
                else                    ((float*)Cv)[idx] = v;
            }
        }
    }
}

// ---------------- windowed attention ----------------
// qkv: [Bc*3136, 2304] bf16, token n = t*49 + w, col = sec*768 + h*64 + d.
// Per block (b,h,w): pool q over stride groups, softmax(q_p k^T / 8) v.
// o: [Bc*784, 768] bf16, row = b*784 + qpos*49 + w, col = h*64 + d.
__global__ __launch_bounds__(256)
void attn_win(const unsigned short* __restrict__ qkv,
              unsigned short* __restrict__ o) {
    const int h = blockIdx.x;    // 12
    const int w = blockIdx.y;    // 49
    const int b = blockIdx.z;    // 8
    __shared__ unsigned short qs[64 * 66];
    __shared__ unsigned short ks_[64 * 66];
    __shared__ unsigned short vs[64 * 66];
    __shared__ unsigned short qp[16 * 66];

    const int tid = threadIdx.x;
    // stage q,k,v tiles: thread loads 16 bf16 (32 B) of one token row
    {
        const int t  = tid >> 2;
        const int c4 = tid & 3;
        const long rowbase =
            ((long)b * 3136 + (long)t * 49 + w) * 2304 + h * 64 + c4 * 16;
        uint4 a0 = *(const uint4*)(qkv + rowbase);
        uint4 a1 = *(const uint4*)(qkv + rowbase + 8);
        uint4 k0 = *(const uint4*)(qkv + rowbase + 768);
        uint4 k1 = *(const uint4*)(qkv + rowbase + 768 + 8);
        uint4 v0 = *(const uint4*)(qkv + rowbase + 1536);
        uint4 v1 = *(const uint4*)(qkv + rowbase + 1536 + 8);
        unsigned* dq = (unsigned*)&qs[t * 66 + c4 * 16];
        unsigned* dk = (unsigned*)&ks_[t * 66 + c4 * 16];
        unsigned* dv = (unsigned*)&vs[t * 66 + c4 * 16];
        dq[0]=a0.x; dq[1]=a0.y; dq[2]=a0.z; dq[3]=a0.w;
        dq[4]=a1.x; dq[5]=a1.y; dq[6]=a1.z; dq[7]=a1.w;
        dk[0]=k0.x; dk[1]=k0.y; dk[2]=k0.z; dk[3]=k0.w;
        dk[4]=k1.x; dk[5]=k1.y; dk[6]=k1.z; dk[7]=k1.w;
        dv[0]=v0.x; dv[1]=v0.y; dv[2]=v0.z; dv[3]=v0.w;
        dv[4]=v1.x; dv[5]=v1.y; dv[6]=v1.z; dv[7]=v1.w;
    }
    __syncthreads();
    // q max-pool over s: qp[j][d] = max_s qs[s*16+j][d]
    {
        const int j  = tid >> 4;           // 0..15
        const int d0 = (tid & 15) * 4;
        #pragma unroll
        for (int dd = 0; dd < 4; ++dd) {
            const int d = d0 + dd;
            float m = bf2f(qs[j * 66 + d]);
            #pragma unroll
            for (int s = 1; s < 4; ++s)
                m = fmaxf(m, bf2f(qs[(s * 16 + j) * 66 + d]));
            qp[j * 66 + d] = f2bf(m);      // lossless: m is a bf16 value
        }
    }
    __syncthreads();

    const int wv = tid >> 6, ln = tid & 63;
    #pragma unroll 1
    for (int p = 0; p < 4; ++p) {
        const int r = wv * 4 + p;          // q row 0..15
        // S[ln] = dot64(qp[r], k[ln]) * 0.125
        float s = 0.f;
        #pragma unroll
        for (int kk = 0; kk < 64; kk += 2) {
            const unsigned uq = *(const unsigned*)&qp[r * 66 + kk];
            const unsigned uk = *(const unsigned*)&ks_[ln * 66 + kk];
            s += __builtin_bit_cast(float, uq << 16) *
                 __builtin_bit_cast(float, uk << 16);
            s += __builtin_bit_cast(float, uq & 0xffff0000u) *
                 __builtin_bit_cast(float, uk & 0xffff0000u);
        }
        s *= 0.125f;
        // softmax across 64 lanes
        float mx = s;
        #pragma unroll
        for (int off = 32; off > 0; off >>= 1)
            mx = fmaxf(mx, __shfl_xor(mx, off));
        const float e = __expf(s - mx);
        float sm = e;
        #pragma unroll
        for (int off = 32; off > 0; off >>= 1)
            sm += __shfl_xor(sm, off);
        const float pr = e / sm;
        // O[r][ln] = sum_t P[t] * v[t][ln]
        float oacc = 0.f;
        for (int t2 = 0; t2 < 64; ++t2) {
            const float pt = __shfl(pr, t2);
            oacc += pt * bf2f(vs[t2 * 66 + ln]);
        }
        const long orow = (long)b * 784 + (long)r * 49 + w;
        o[orow * 768 + h * 64 + ln] = f2bf(oacc);
    }
}

// ---------------- launcher ----------------
extern "C" void kernel_launch(void* const* d_in, const int* in_sizes, int n_in,
                              void* d_out, int out_size, void* d_ws, size_t ws_size,
                              hipStream_t stream) {
    const float* x     = (const float*)d_in[0];  // [32,3136,768]
    const float* Wqkv  = (const float*)d_in[1];  // [768,2304]
    const float* bqkv  = (const float*)d_in[2];  // [2304]
    const float* Wproj = (const float*)d_in[3];  // [768,768]
    const float* bproj = (const float*)d_in[4];  // [768]
    float* out = (float*)d_out;                  // [32,784,768] fp32

    const long XC = 8L * 3136 * 768;             // x elems per chunk (=19267584)
    char* p = (char*)d_ws;
    unsigned short* xb    = (unsigned short*)p; p += XC * 2;
    unsigned short* qkvb  = (unsigned short*)p; p += 8L * 3136 * 2304 * 2;
    unsigned short* ob    = (unsigned short*)p; p += 25088L * 768 * 2;
    unsigned short* WqkvT = (unsigned short*)p; p += 2304L * 768 * 2;
    unsigned short* WprojT= (unsigned short*)p; p += 768L * 768 * 2;

    transpose_cvt<<<dim3(2304 / 32, 768 / 32), 256, 0, stream>>>(Wqkv, WqkvT, 768, 2304);
    transpose_cvt<<<dim3(768 / 32, 768 / 32), 256, 0, stream>>>(Wproj, WprojT, 768, 768);

    for (int c = 0; c < 4; ++c) {
        cvt_f32_bf16<<<(int)(XC / 4 / 256), 256, 0, stream>>>(x + (size_t)c * XC, xb, XC / 4);
        gemm_bt<true><<<dim3(2304 / 128, 25088 / 128), 256, 0, stream>>>(
            xb, WqkvT, bqkv, qkvb, 25088, 2304, 768);
        attn_win<<<dim3(12, 49, 8), 256, 0, stream>>>(qkvb, ob + (size_t)c * 6272 * 768);
    }
    gemm_bt<false><<<dim3(768 / 128, 25088 / 128), 256, 0, stream>>>(
        ob, WprojT, bproj, out, 25088, 768, 768);
}

// Round 2
// 1275.450 us; speedup vs baseline: 1.1578x; 1.1578x over previous
//
#include <hip/hip_runtime.h>
#include <hip/hip_bf16.h>

// MultiScaleAttention on MI355X (gfx950).
// cvt(x)->bf16; QKV GEMM (bf16 MFMA, fp32 acc); MFMA windowed attention
// (wave-per-head-window, q max-pool fused, P/vT via wave-private LDS);
// proj GEMM -> fp32 out. Chunking auto-disabled when ws_size allows (~660MB).

typedef __bf16 bf16x8 __attribute__((ext_vector_type(8)));
typedef float f32x4 __attribute__((ext_vector_type(4)));
typedef unsigned short u16x8 __attribute__((ext_vector_type(8)));

#define GLOBAL_AS __attribute__((address_space(1)))
#define LDS_AS __attribute__((address_space(3)))

__device__ __forceinline__ unsigned short f2bf(float f) {
    unsigned u = __builtin_bit_cast(unsigned, f);
    u += 0x7FFFu + ((u >> 16) & 1u);           // round-to-nearest-even
    return (unsigned short)(u >> 16);
}
__device__ __forceinline__ float bf2f(unsigned short h) {
    return __builtin_bit_cast(float, (unsigned)h << 16);
}

__device__ __forceinline__ void load16_to_lds(const void* g, void* l) {
    __builtin_amdgcn_global_load_lds((const GLOBAL_AS unsigned int*)g,
                                     (LDS_AS unsigned int*)l, 16, 0, 0);
}

// ---------------- elementwise fp32 -> bf16 ----------------
__global__ void cvt_f32_bf16(const float* __restrict__ in,
                             unsigned short* __restrict__ out, long n4) {
    long i = (long)blockIdx.x * blockDim.x + threadIdx.x;
    if (i >= n4) return;
    float4 f = ((const float4*)in)[i];
    uint2 u;
    u.x = (unsigned)f2bf(f.x) | ((unsigned)f2bf(f.y) << 16);
    u.y = (unsigned)f2bf(f.z) | ((unsigned)f2bf(f.w) << 16);
    ((uint2*)out)[i] = u;
}

// ---------------- W[K][N] fp32 -> Wt[N][K] bf16 ----------------
__global__ void transpose_cvt(const float* __restrict__ W,
                              unsigned short* __restrict__ Wt, int K, int N) {
    __shared__ float tile[32][33];
    int bx = blockIdx.x * 32;                  // N offset
    int by = blockIdx.y * 32;                  // K offset
    int tx = threadIdx.x & 31, ty = threadIdx.x >> 5;   // ty 0..7
    #pragma unroll
    for (int i = 0; i < 32; i += 8)
        tile[ty + i][tx] = W[(size_t)(by + ty + i) * N + bx + tx];
    __syncthreads();
    #pragma unroll
    for (int i = 0; i < 32; i += 8)
        Wt[(size_t)(bx + ty + i) * K + by + tx] = f2bf(tile[tx][ty + i]);
}

// ---------------- bf16 GEMM: C[M,N] = A[M,K] @ Bt[N,K]^T + bias ----------------
// 128x128 tile, BK=64, 256 threads = 4 waves (2x2 of 64x64), mfma 16x16x32.
template <bool OUT_BF16>
__global__ __launch_bounds__(256)
void gemm_bt(const unsigned short* __restrict__ A,
             const unsigned short* __restrict__ Bt,
             const float* __restrict__ bias,
             void* __restrict__ Cv, int M, int N, int K) {
    __shared__ alignas(16) unsigned short lsA[128 * 64];
    __shared__ alignas(16) unsigned short lsB[128 * 64];

    const int tid  = threadIdx.x;
    const int lane = tid & 63;
    const int wave = tid >> 6;
    const int wm = (wave >> 1) * 64;
    const int wn = (wave & 1) * 64;
    const long bm = (long)blockIdx.y * 128;
    const long bn = (long)blockIdx.x * 128;

    const int arow  = tid >> 3;                // 0..31, +32 per it
    const int acolb = (tid & 7) * 16;          // byte col within 128-B row
    const char* gA = (const char*)A + ((bm + arow) * (long)K) * 2 + acolb;
    const char* gB = (const char*)Bt + ((bn + arow) * (long)K) * 2 + acolb;
    const long rowStep = (long)K * 2 * 32;     // 32 rows ahead per 'it'
    const int ldsWaveBase = wave * 512;        // ushort units

    f32x4 acc[4][4] = {};

    for (int kt = 0; kt < K; kt += 64) {
        #pragma unroll
        for (int it = 0; it < 4; ++it) {
            load16_to_lds(gA + it * rowStep, &lsA[it * 2048 + ldsWaveBase]);
            load16_to_lds(gB + it * rowStep, &lsB[it * 2048 + ldsWaveBase]);
        }
        gA += 128; gB += 128;                  // advance 64 bf16 in K
        __syncthreads();
        #pragma unroll
        for (int ks = 0; ks < 64; ks += 32) {
            bf16x8 af[4], bg[4];
            const int koff = ks + (lane >> 4) * 8;
            #pragma unroll
            for (int i = 0; i < 4; ++i) {
                const int rowA = wm + i * 16 + (lane & 15);
                af[i] = *(const bf16x8*)&lsA[rowA * 64 + koff];
                const int rowB = wn + i * 16 + (lane & 15);
                bg[i] = *(const bf16x8*)&lsB[rowB * 64 + koff];
            }
            #pragma unroll
            for (int i = 0; i < 4; ++i)
                #pragma unroll
                for (int j = 0; j < 4; ++j)
                    acc[i][j] = __builtin_amdgcn_mfma_f32_16x16x32_bf16(
                        af[i], bg[j], acc[i][j], 0, 0, 0);
        }
        __syncthreads();
    }

    const long rbase = bm + wm + (lane >> 4) * 4;
    const int  cbase = (int)bn + wn + (lane & 15);
    #pragma unroll
    for (int j = 0; j < 4; ++j) {
        const int col = cbase + j * 16;
        const float bv = bias[col];
        #pragma unroll
        for (int i = 0; i < 4; ++i) {
            const long row0 = rbase + i * 16;
            #pragma unroll
            for (int r = 0; r < 4; ++r) {
                const float v = acc[i][j][r] + bv;
                const size_t idx = (size_t)(row0 + r) * N + col;
                if constexpr (OUT_BF16) ((unsigned short*)Cv)[idx] = f2bf(v);
                else                    ((float*)Cv)[idx] = v;
            }
        }
    }
}

// ---------------- MFMA windowed attention ----------------
// One wave = one (b, w, head). 4 waves/block -> 4 heads (hg*4 + wave).
// qkv rows: token n = t*49 + w (t in [0,64)), cols sec*768 + h*64 + d.
// Pool q over token groups {j, j+16, j+32, j+48} -> qp[16][64] (in regs,
// pre-scaled by 0.125). S = qp @ k^T via 8 mfma (k frags from global).
// Softmax across 16 lanes + 4 n-tiles. P -> LDS -> A-frags. v staged
// transposed in LDS -> B-frags. O = P@v via 8 mfma. No __syncthreads.
__global__ __launch_bounds__(256)
void attn_win_mfma(const unsigned short* __restrict__ qkv,
                   unsigned short* __restrict__ o) {
    const int hg = blockIdx.x;       // 0..2
    const int w  = blockIdx.y;       // 0..48
    const int b  = blockIdx.z;       // batch within chunk
    const int wave = threadIdx.x >> 6;
    const int lane = threadIdx.x & 63;
    const int h = hg * 4 + wave;
    const int l = lane & 15;
    const int quad = lane >> 4;

    __shared__ alignas(16) unsigned short vT[4][64 * 72];  // [d][t], stride 72
    __shared__ alignas(16) unsigned short ps[4][16 * 72];  // P[q][key], stride 72

    const long tokStride = 49L * 2304;
    const long base = ((long)b * 3136 + w) * 2304 + h * 64;

    // ---- q load + max-pool + 0.125 scale (exact in bf16) -> A-frags ----
    bf16x8 af[2];
    {
        const unsigned short* qr = qkv + base + (long)l * tokStride + quad * 8;
        float m0[8], m1[8];
        #pragma unroll
        for (int sg = 0; sg < 4; ++sg) {
            uint4 u0 = *(const uint4*)(qr + (long)sg * 16 * tokStride);
            uint4 u1 = *(const uint4*)(qr + (long)sg * 16 * tokStride + 32);
            const unsigned short* p0 = (const unsigned short*)&u0;
            const unsigned short* p1 = (const unsigned short*)&u1;
            #pragma unroll
            for (int e = 0; e < 8; ++e) {
                float f0 = bf2f(p0[e]), f1 = bf2f(p1[e]);
                if (sg == 0) { m0[e] = f0; m1[e] = f1; }
                else { m0[e] = fmaxf(m0[e], f0); m1[e] = fmaxf(m1[e], f1); }
            }
        }
        u16x8 a0, a1;
        #pragma unroll
        for (int e = 0; e < 8; ++e) {
            a0[e] = f2bf(m0[e] * 0.125f);
            a1[e] = f2bf(m1[e] * 0.125f);
        }
        af[0] = __builtin_bit_cast(bf16x8, a0);
        af[1] = __builtin_bit_cast(bf16x8, a1);
    }

    // ---- v: stage transposed into LDS ----
    {
        const unsigned short* vr = qkv + base + (long)lane * tokStride + 1536;
        unsigned short* vw = &vT[wave][0];
        #pragma unroll
        for (int i = 0; i < 8; ++i) {
            uint4 u = *(const uint4*)(vr + i * 8);
            const unsigned short* pe = (const unsigned short*)&u;
            #pragma unroll
            for (int e = 0; e < 8; ++e)
                vw[(i * 8 + e) * 72 + lane] = pe[e];
        }
    }

    // ---- k B-frags from global; S = qp @ k^T ----
    f32x4 Sc[4] = {};
    {
        bf16x8 bk0, bk1;
        #pragma unroll
        for (int tt = 0; tt < 4; ++tt) {
            const unsigned short* kr =
                qkv + base + (long)(tt * 16 + l) * tokStride + 768 + quad * 8;
            bk0 = __builtin_bit_cast(bf16x8, *(const uint4*)kr);
            bk1 = __builtin_bit_cast(bf16x8, *(const uint4*)(kr + 32));
            Sc[tt] = __builtin_amdgcn_mfma_f32_16x16x32_bf16(af[0], bk0, Sc[tt], 0, 0, 0);
            Sc[tt] = __builtin_amdgcn_mfma_f32_16x16x32_bf16(af[1], bk1, Sc[tt], 0, 0, 0);
        }
    }

    // ---- softmax: row q = quad*4+r, keys spread over 4 tt x 16 lanes ----
    float pr[4][4];
    {
        #pragma unroll
        for (int r = 0; r < 4; ++r) {
            float mx = fmaxf(fmaxf(Sc[0][r], Sc[1][r]), fmaxf(Sc[2][r], Sc[3][r]));
            #pragma unroll
            for (int off = 1; off < 16; off <<= 1)
                mx = fmaxf(mx, __shfl_xor(mx, off));
            float sum = 0.f;
            #pragma unroll
            for (int tt = 0; tt < 4; ++tt) {
                pr[tt][r] = __expf(Sc[tt][r] - mx);
                sum += pr[tt][r];
            }
            #pragma unroll
            for (int off = 1; off < 16; off <<= 1)
                sum += __shfl_xor(sum, off);
            const float inv = 1.0f / sum;
            #pragma unroll
            for (int tt = 0; tt < 4; ++tt) pr[tt][r] *= inv;
        }
    }

    // ---- P -> LDS (bf16) ----
    {
        unsigned short* pw = &ps[wave][0];
        #pragma unroll
        for (int r = 0; r < 4; ++r)
            #pragma unroll
            for (int tt = 0; tt < 4; ++tt)
                pw[(quad * 4 + r) * 72 + tt * 16 + l] = f2bf(pr[tt][r]);
    }

    // ---- O = P @ v ----
    f32x4 Oc[4] = {};
    {
        #pragma unroll
        for (int s = 0; s < 2; ++s) {
            bf16x8 ap = *(const bf16x8*)&ps[wave][l * 72 + s * 32 + quad * 8];
            #pragma unroll
            for (int tt = 0; tt < 4; ++tt) {
                bf16x8 bv = *(const bf16x8*)&vT[wave][(tt * 16 + l) * 72 + s * 32 + quad * 8];
                Oc[tt] = __builtin_amdgcn_mfma_f32_16x16x32_bf16(ap, bv, Oc[tt], 0, 0, 0);
            }
        }
    }

    // ---- store: o row = b*784 + q*49 + w, col = h*64 + tt*16 + l ----
    {
        const long obase = ((long)b * 784 + (long)(quad * 4) * 49 + w) * 768 + h * 64 + l;
        #pragma unroll
        for (int tt = 0; tt < 4; ++tt)
            #pragma unroll
            for (int r = 0; r < 4; ++r)
                o[obase + (long)r * 49 * 768 + tt * 16] = f2bf(Oc[tt][r]);
    }
}

// ---------------- launcher ----------------
extern "C" void kernel_launch(void* const* d_in, const int* in_sizes, int n_in,
                              void* d_out, int out_size, void* d_ws, size_t ws_size,
                              hipStream_t stream) {
    const float* x     = (const float*)d_in[0];  // [32,3136,768]
    const float* Wqkv  = (const float*)d_in[1];  // [768,2304]
    const float* bqkv  = (const float*)d_in[2];  // [2304]
    const float* Wproj = (const float*)d_in[3];  // [768,768]
    const float* bproj = (const float*)d_in[4];  // [768]
    float* out = (float*)d_out;                  // [32,784,768] fp32

    const long needed1 = (32L * 3136 * 768 + 32L * 3136 * 2304 +
                          25088L * 768 + 2304L * 768 + 768L * 768) * 2;
    const int C  = (ws_size >= (size_t)needed1) ? 1 : 4;   // unchunked if ws allows
    const int CB = 32 / C;
    const long XC = (long)CB * 3136 * 768;
    const long QC = (long)CB * 3136 * 2304;

    char* p = (char*)d_ws;
    unsigned short* xb    = (unsigned short*)p; p += XC * 2;
    unsigned short* qkvb  = (unsigned short*)p; p += QC * 2;
    unsigned short* ob    = (unsigned short*)p; p += 25088L * 768 * 2;
    unsigned short* WqkvT = (unsigned short*)p; p += 2304L * 768 * 2;
    unsigned short* WprojT= (unsigned short*)p; p += 768L * 768 * 2;

    transpose_cvt<<<dim3(72, 24), 256, 0, stream>>>(Wqkv, WqkvT, 768, 2304);
    transpose_cvt<<<dim3(24, 24), 256, 0, stream>>>(Wproj, WprojT, 768, 768);

    const int M = CB * 3136;
    for (int c = 0; c < C; ++c) {
        cvt_f32_bf16<<<(int)(XC / 4 / 256), 256, 0, stream>>>(x + (size_t)c * XC, xb, XC / 4);
        gemm_bt<true><<<dim3(18, M / 128), 256, 0, stream>>>(
            xb, WqkvT, bqkv, qkvb, M, 2304, 768);
        attn_win_mfma<<<dim3(3, 49, CB), 256, 0, stream>>>(
            qkvb, ob + (size_t)c * CB * 784 * 768);
    }
    gemm_bt<false><<<dim3(6, 196), 256, 0, stream>>>(
        ob, WprojT, bproj, out, 25088, 768, 768);
}

// Round 3
// 1227.355 us; speedup vs baseline: 1.2031x; 1.0392x over previous
//
#include <hip/hip_runtime.h>
#include <hip/hip_bf16.h>

// MultiScaleAttention on MI355X (gfx950).
// cvt(x)->bf16; QKV GEMM (bf16 MFMA, fp32 acc, XOR-swizzled LDS);
// MFMA windowed attention; proj GEMM -> fp32 out. Unchunked (ws ~660MB ok).

typedef __bf16 bf16x8 __attribute__((ext_vector_type(8)));
typedef float f32x4 __attribute__((ext_vector_type(4)));
typedef unsigned short u16x8 __attribute__((ext_vector_type(8)));

#define GLOBAL_AS __attribute__((address_space(1)))
#define LDS_AS __attribute__((address_space(3)))

__device__ __forceinline__ unsigned short f2bf(float f) {
    unsigned u = __builtin_bit_cast(unsigned, f);
    u += 0x7FFFu + ((u >> 16) & 1u);           // round-to-nearest-even
    return (unsigned short)(u >> 16);
}
__device__ __forceinline__ float bf2f(unsigned short h) {
    return __builtin_bit_cast(float, (unsigned)h << 16);
}

__device__ __forceinline__ void load16_to_lds(const void* g, void* l) {
    __builtin_amdgcn_global_load_lds((const GLOBAL_AS unsigned int*)g,
                                     (LDS_AS unsigned int*)l, 16, 0, 0);
}

// ---------------- elementwise fp32 -> bf16 ----------------
__global__ void cvt_f32_bf16(const float* __restrict__ in,
                             unsigned short* __restrict__ out, long n4) {
    long i = (long)blockIdx.x * blockDim.x + threadIdx.x;
    if (i >= n4) return;
    float4 f = ((const float4*)in)[i];
    uint2 u;
    u.x = (unsigned)f2bf(f.x) | ((unsigned)f2bf(f.y) << 16);
    u.y = (unsigned)f2bf(f.z) | ((unsigned)f2bf(f.w) << 16);
    ((uint2*)out)[i] = u;
}

// ---------------- W[K][N] fp32 -> Wt[N][K] bf16 ----------------
__global__ void transpose_cvt(const float* __restrict__ W,
                              unsigned short* __restrict__ Wt, int K, int N) {
    __shared__ float tile[32][33];
    int bx = blockIdx.x * 32;                  // N offset
    int by = blockIdx.y * 32;                  // K offset
    int tx = threadIdx.x & 31, ty = threadIdx.x >> 5;   // ty 0..7
    #pragma unroll
    for (int i = 0; i < 32; i += 8)
        tile[ty + i][tx] = W[(size_t)(by + ty + i) * N + bx + tx];
    __syncthreads();
    #pragma unroll
    for (int i = 0; i < 32; i += 8)
        Wt[(size_t)(bx + ty + i) * K + by + tx] = f2bf(tile[tx][ty + i]);
}

// ---------------- bf16 GEMM: C[M,N] = A[M,K] @ Bt[N,K]^T + bias ----------------
// 128x128 tile, BK=64, 256 threads = 4 waves (2x2 of 64x64), mfma 16x16x32.
// LDS XOR swizzle: physical 16B chunk p of row r holds logical chunk p^(r&7).
// Staging permutes the GLOBAL source chunk per lane (global_load_lds dest is
// fixed at base+lane*16); fragment reads XOR the column. Kills the 16-way
// bank conflict of the 128B-row-stride layout (r2: SQ_LDS_BANK_CONFLICT 1.3e8).
template <bool OUT_BF16>
__global__ __launch_bounds__(256)
void gemm_bt(const unsigned short* __restrict__ A,
             const unsigned short* __restrict__ Bt,
             const float* __restrict__ bias,
             void* __restrict__ Cv, int M, int N, int K) {
    __shared__ alignas(16) unsigned short lsA[128 * 64];
    __shared__ alignas(16) unsigned short lsB[128 * 64];

    const int tid  = threadIdx.x;
    const int lane = tid & 63;
    const int wave = tid >> 6;
    const int wm = (wave >> 1) * 64;
    const int wn = (wave & 1) * 64;
    const long bm = (long)blockIdx.y * 128;
    const long bn = (long)blockIdx.x * 128;

    const int arow  = tid >> 3;                               // 0..31, +32 per it
    const int acolb = (((tid & 7) ^ ((tid >> 3) & 7)) * 16);  // swizzled byte col
    const char* gA = (const char*)A + ((bm + arow) * (long)K) * 2 + acolb;
    const char* gB = (const char*)Bt + ((bn + arow) * (long)K) * 2 + acolb;
    const long rowStep = (long)K * 2 * 32;     // 32 rows ahead per 'it' (row&7 invariant)
    const int ldsWaveBase = wave * 512;        // ushort units

    f32x4 acc[4][4] = {};

    for (int kt = 0; kt < K; kt += 64) {
        #pragma unroll
        for (int it = 0; it < 4; ++it) {
            load16_to_lds(gA + it * rowStep, &lsA[it * 2048 + ldsWaveBase]);
            load16_to_lds(gB + it * rowStep, &lsB[it * 2048 + ldsWaveBase]);
        }
        gA += 128; gB += 128;                  // advance 64 bf16 in K
        __syncthreads();
        #pragma unroll
        for (int ks = 0; ks < 64; ks += 32) {
            bf16x8 af[4], bg[4];
            // rowA&7 == lane&7 for all i (wm, i*16 are multiples of 8)
            const int colSwz = (ks + (lane >> 4) * 8) ^ ((lane & 7) * 8);
            #pragma unroll
            for (int i = 0; i < 4; ++i) {
                const int rowA = wm + i * 16 + (lane & 15);
                af[i] = *(const bf16x8*)&lsA[rowA * 64 + colSwz];
                const int rowB = wn + i * 16 + (lane & 15);
                bg[i] = *(const bf16x8*)&lsB[rowB * 64 + colSwz];
            }
            #pragma unroll
            for (int i = 0; i < 4; ++i)
                #pragma unroll
                for (int j = 0; j < 4; ++j)
                    acc[i][j] = __builtin_amdgcn_mfma_f32_16x16x32_bf16(
                        af[i], bg[j], acc[i][j], 0, 0, 0);
        }
        __syncthreads();
    }

    const long rbase = bm + wm + (lane >> 4) * 4;
    const int  cbase = (int)bn + wn + (lane & 15);
    #pragma unroll
    for (int j = 0; j < 4; ++j) {
        const int col = cbase + j * 16;
        const float bv = bias[col];
        #pragma unroll
        for (int i = 0; i < 4; ++i) {
            const long row0 = rbase + i * 16;
            #pragma unroll
            for (int r = 0; r < 4; ++r) {
                const float v = acc[i][j][r] + bv;
                const size_t idx = (size_t)(row0 + r) * N + col;
                if constexpr (OUT_BF16) ((unsigned short*)Cv)[idx] = f2bf(v);
                else                    ((float*)Cv)[idx] = v;
            }
        }
    }
}

// ---------------- MFMA windowed attention ----------------
// One wave = one (b, w, head). 4 waves/block -> 4 heads (hg*4 + wave).
// qkv rows: token n = t*49 + w (t in [0,64)), cols sec*768 + h*64 + d.
// Pool q over token groups {j, j+16, j+32, j+48} -> qp[16][64] (in regs,
// pre-scaled by 0.125). S = qp @ k^T via 8 mfma (k frags from global).
// Softmax across 16 lanes + 4 n-tiles. P -> LDS -> A-frags. v staged
// transposed in LDS -> B-frags. O = P@v via 8 mfma. No __syncthreads.
__global__ __launch_bounds__(256)
void attn_win_mfma(const unsigned short* __restrict__ qkv,
                   unsigned short* __restrict__ o) {
    const int hg = blockIdx.x;       // 0..2
    const int w  = blockIdx.y;       // 0..48
    const int b  = blockIdx.z;       // batch within chunk
    const int wave = threadIdx.x >> 6;
    const int lane = threadIdx.x & 63;
    const int h = hg * 4 + wave;
    const int l = lane & 15;
    const int quad = lane >> 4;

    __shared__ alignas(16) unsigned short vT[4][64 * 72];  // [d][t], stride 72
    __shared__ alignas(16) unsigned short ps[4][16 * 72];  // P[q][key], stride 72

    const long tokStride = 49L * 2304;
    const long base = ((long)b * 3136 + w) * 2304 + h * 64;

    // ---- q load + max-pool + 0.125 scale (exact in bf16) -> A-frags ----
    bf16x8 af[2];
    {
        const unsigned short* qr = qkv + base + (long)l * tokStride + quad * 8;
        float m0[8], m1[8];
        #pragma unroll
        for (int sg = 0; sg < 4; ++sg) {
            uint4 u0 = *(const uint4*)(qr + (long)sg * 16 * tokStride);
            uint4 u1 = *(const uint4*)(qr + (long)sg * 16 * tokStride + 32);
            const unsigned short* p0 = (const unsigned short*)&u0;
            const unsigned short* p1 = (const unsigned short*)&u1;
            #pragma unroll
            for (int e = 0; e < 8; ++e) {
                float f0 = bf2f(p0[e]), f1 = bf2f(p1[e]);
                if (sg == 0) { m0[e] = f0; m1[e] = f1; }
                else { m0[e] = fmaxf(m0[e], f0); m1[e] = fmaxf(m1[e], f1); }
            }
        }
        u16x8 a0, a1;
        #pragma unroll
        for (int e = 0; e < 8; ++e) {
            a0[e] = f2bf(m0[e] * 0.125f);
            a1[e] = f2bf(m1[e] * 0.125f);
        }
        af[0] = __builtin_bit_cast(bf16x8, a0);
        af[1] = __builtin_bit_cast(bf16x8, a1);
    }

    // ---- v: stage transposed into LDS ----
    {
        const unsigned short* vr = qkv + base + (long)lane * tokStride + 1536;
        unsigned short* vw = &vT[wave][0];
        #pragma unroll
        for (int i = 0; i < 8; ++i) {
            uint4 u = *(const uint4*)(vr + i * 8);
            const unsigned short* pe = (const unsigned short*)&u;
            #pragma unroll
            for (int e = 0; e < 8; ++e)
                vw[(i * 8 + e) * 72 + lane] = pe[e];
        }
    }

    // ---- k B-frags from global; S = qp @ k^T ----
    f32x4 Sc[4] = {};
    {
        bf16x8 bk0, bk1;
        #pragma unroll
        for (int tt = 0; tt < 4; ++tt) {
            const unsigned short* kr =
                qkv + base + (long)(tt * 16 + l) * tokStride + 768 + quad * 8;
            bk0 = __builtin_bit_cast(bf16x8, *(const uint4*)kr);
            bk1 = __builtin_bit_cast(bf16x8, *(const uint4*)(kr + 32));
            Sc[tt] = __builtin_amdgcn_mfma_f32_16x16x32_bf16(af[0], bk0, Sc[tt], 0, 0, 0);
            Sc[tt] = __builtin_amdgcn_mfma_f32_16x16x32_bf16(af[1], bk1, Sc[tt], 0, 0, 0);
        }
    }

    // ---- softmax: row q = quad*4+r, keys spread over 4 tt x 16 lanes ----
    float pr[4][4];
    {
        #pragma unroll
        for (int r = 0; r < 4; ++r) {
            float mx = fmaxf(fmaxf(Sc[0][r], Sc[1][r]), fmaxf(Sc[2][r], Sc[3][r]));
            #pragma unroll
            for (int off = 1; off < 16; off <<= 1)
                mx = fmaxf(mx, __shfl_xor(mx, off));
            float sum = 0.f;
            #pragma unroll
            for (int tt = 0; tt < 4; ++tt) {
                pr[tt][r] = __expf(Sc[tt][r] - mx);
                sum += pr[tt][r];
            }
            #pragma unroll
            for (int off = 1; off < 16; off <<= 1)
                sum += __shfl_xor(sum, off);
            const float inv = 1.0f / sum;
            #pragma unroll
            for (int tt = 0; tt < 4; ++tt) pr[tt][r] *= inv;
        }
    }

    // ---- P -> LDS (bf16) ----
    {
        unsigned short* pw = &ps[wave][0];
        #pragma unroll
        for (int r = 0; r < 4; ++r)
            #pragma unroll
            for (int tt = 0; tt < 4; ++tt)
                pw[(quad * 4 + r) * 72 + tt * 16 + l] = f2bf(pr[tt][r]);
    }

    // ---- O = P @ v ----
    f32x4 Oc[4] = {};
    {
        #pragma unroll
        for (int s = 0; s < 2; ++s) {
            bf16x8 ap = *(const bf16x8*)&ps[wave][l * 72 + s * 32 + quad * 8];
            #pragma unroll
            for (int tt = 0; tt < 4; ++tt) {
                bf16x8 bv = *(const bf16x8*)&vT[wave][(tt * 16 + l) * 72 + s * 32 + quad * 8];
                Oc[tt] = __builtin_amdgcn_mfma_f32_16x16x32_bf16(ap, bv, Oc[tt], 0, 0, 0);
            }
        }
    }

    // ---- store: o row = b*784 + q*49 + w, col = h*64 + tt*16 + l ----
    {
        const long obase = ((long)b * 784 + (long)(quad * 4) * 49 + w) * 768 + h * 64 + l;
        #pragma unroll
        for (int tt = 0; tt < 4; ++tt)
            #pragma unroll
            for (int r = 0; r < 4; ++r)
                o[obase + (long)r * 49 * 768 + tt * 16] = f2bf(Oc[tt][r]);
    }
}

// ---------------- launcher ----------------
extern "C" void kernel_launch(void* const* d_in, const int* in_sizes, int n_in,
                              void* d_out, int out_size, void* d_ws, size_t ws_size,
                              hipStream_t stream) {
    const float* x     = (const float*)d_in[0];  // [32,3136,768]
    const float* Wqkv  = (const float*)d_in[1];  // [768,2304]
    const float* bqkv  = (const float*)d_in[2];  // [2304]
    const float* Wproj = (const float*)d_in[3];  // [768,768]
    const float* bproj = (const float*)d_in[4];  // [768]
    float* out = (float*)d_out;                  // [32,784,768] fp32

    const long needed1 = (32L * 3136 * 768 + 32L * 3136 * 2304 +
                          25088L * 768 + 2304L * 768 + 768L * 768) * 2;
    const int C  = (ws_size >= (size_t)needed1) ? 1 : 4;   // unchunked if ws allows
    const int CB = 32 / C;
    const long XC = (long)CB * 3136 * 768;
    const long QC = (long)CB * 3136 * 2304;

    char* p = (char*)d_ws;
    unsigned short* xb    = (unsigned short*)p; p += XC * 2;
    unsigned short* qkvb  = (unsigned short*)p; p += QC * 2;
    unsigned short* ob    = (unsigned short*)p; p += 25088L * 768 * 2;
    unsigned short* WqkvT = (unsigned short*)p; p += 2304L * 768 * 2;
    unsigned short* WprojT= (unsigned short*)p; p += 768L * 768 * 2;

    transpose_cvt<<<dim3(72, 24), 256, 0, stream>>>(Wqkv, WqkvT, 768, 2304);
    transpose_cvt<<<dim3(24, 24), 256, 0, stream>>>(Wproj, WprojT, 768, 768);

    const int M = CB * 3136;
    for (int c = 0; c < C; ++c) {
        cvt_f32_bf16<<<(int)(XC / 4 / 256), 256, 0, stream>>>(x + (size_t)c * XC, xb, XC / 4);
        gemm_bt<true><<<dim3(18, M / 128), 256, 0, stream>>>(
            xb, WqkvT, bqkv, qkvb, M, 2304, 768);
        attn_win_mfma<<<dim3(3, 49, CB), 256, 0, stream>>>(
            qkvb, ob + (size_t)c * CB * 784 * 768);
    }
    gemm_bt<false><<<dim3(6, 196), 256, 0, stream>>>(
        ob, WprojT, bproj, out, 25088, 768, 768);
}